// Round 3
// baseline (275.135 us; speedup 1.0000x reference)
//
#include <hip/hip_runtime.h>
#include <math.h>

// AdaptiveSelection on MI355X (gfx950)
// Inputs (fp32): cluster_features (8,4096,1024), key_feats (8,1,1024),
//                q_w (128,1024), q_b (128), v_w (1024,1024), v_b (1024)
// Outputs (fp32, concat): selected (1024,1024) then fus (8,1024)
//
// Algebra:
//   logit_i = f_i . w_c where w_c = q_w^T (q_w key_c + q_b)/sqrt(128) (+const, dropped)
//   topk-128 by logit == topk by softmax (monotone)
//   fusion = v_w @ (A^T feats) + v_b     (sum A = 1)
// Ranking: 64-bit sortable key (ordered float bits << 32 | ~index) makes the
// reference's (value desc, index asc) order a single unsigned compare.

#define DIM   1024
#define NC    8
#define NPER  4096
#define QD    128
#define TOPK  128
#define K1B   128     // blocks per cluster in main streaming pass (4 blocks/CU)

typedef unsigned long long u64;
typedef __attribute__((ext_vector_type(2))) unsigned long long ull2;

// ---------------- K0: fused prep -> w_all (8,1024) ----------------
// grid (NC*4), 256 threads. Each block redundantly computes qk (L2-hot q_w),
// then produces 256 elements of w_c.
__global__ __launch_bounds__(256) void k0_prep(
    const float* __restrict__ key_feats, const float* __restrict__ q_w,
    const float* __restrict__ q_b, float* __restrict__ w_all)
{
    const int c  = blockIdx.x >> 2, jc = blockIdx.x & 3;
    const int tid = threadIdx.x;
    __shared__ float part[256];
    __shared__ float qs[QD];

    {   // phase 1: qk[k] = dot(q_w[k], key_c) + q_b[k]; 2 threads per k
        const int k = tid >> 1, half = tid & 1;
        const float4* qr4 = (const float4*)(q_w + (size_t)k * DIM + half * 512);
        const float4* kf4 = (const float4*)(key_feats + (size_t)c * DIM + half * 512);
        float s = 0.f;
        #pragma unroll 16
        for (int j = 0; j < 128; ++j) {
            float4 a = qr4[j], b = kf4[j];
            s += a.x*b.x + a.y*b.y + a.z*b.z + a.w*b.w;
        }
        part[tid] = s;
    }
    __syncthreads();
    if (tid < QD) qs[tid] = part[2*tid] + part[2*tid+1] + q_b[tid];
    __syncthreads();

    // phase 2: w[j] = sum_k q_w[k][j] * qk[k] / sqrt(128); coalesced over j
    const int j = jc * 256 + tid;
    float s = 0.f;
    #pragma unroll 16
    for (int k = 0; k < QD; ++k)
        s += q_w[(size_t)k * DIM + j] * qs[k];
    w_all[c * DIM + j] = s * 0.08838834764831845f; // 1/sqrt(128)
}

// ---------------- K1: fused logits(keys) + online-softmax weighted row sum ----------
// grid (K1B, NC), block 256 = 4 waves; one wave per row; 8 rows/wave; dbuf prefetch.
__global__ __launch_bounds__(256, 4) void k1_main(
    const float* __restrict__ feats, const float* __restrict__ w_all,
    u64* __restrict__ keys,            // (8,4096) sortable keys
    float* __restrict__ pacc,          // (8*K1B,1024)
    float* __restrict__ pm, float* __restrict__ pz)  // (8*K1B)
{
    const int c    = blockIdx.y;
    const int blk  = blockIdx.x;
    const int tid  = threadIdx.x;
    const int lane = tid & 63;
    const int wave = tid >> 6;

    const float4* w4 = (const float4*)(w_all + c * DIM);
    float4 wv[4];
    #pragma unroll
    for (int q = 0; q < 4; ++q) wv[q] = w4[lane + 64*q];

    float4 acc[4];
    #pragma unroll
    for (int q = 0; q < 4; ++q) acc[q] = make_float4(0.f, 0.f, 0.f, 0.f);
    float m = -INFINITY, Z = 0.f;

    const int wslot = blk * 4 + wave;          // 0..511
    const float* fc = feats + (size_t)c * NPER * DIM;

    float4 fA[4], fB[4];
    {
        const float4* f4 = (const float4*)(fc + (size_t)wslot * DIM);
        #pragma unroll
        for (int q = 0; q < 4; ++q) fA[q] = f4[lane + 64*q];
    }

    #define K1_PROCESS(FREG, ROW)                                              \
    do {                                                                       \
        float p = 0.f;                                                         \
        _Pragma("unroll")                                                      \
        for (int q = 0; q < 4; ++q)                                            \
            p += FREG[q].x*wv[q].x + FREG[q].y*wv[q].y +                       \
                 FREG[q].z*wv[q].z + FREG[q].w*wv[q].w;                        \
        _Pragma("unroll")                                                      \
        for (int off = 32; off > 0; off >>= 1) p += __shfl_xor(p, off, 64);    \
        if (lane == 0) {                                                       \
            unsigned int b = __float_as_uint(p);                               \
            unsigned int u = b ^ ((b & 0x80000000u) ? 0xFFFFFFFFu : 0x80000000u); \
            keys[c * NPER + (ROW)] = ((u64)u << 32) | (unsigned int)(~(ROW));  \
        }                                                                      \
        const float mn   = fmaxf(m, p);                                        \
        const float sOld = __expf(m - mn);                                     \
        const float t    = __expf(p - mn);                                     \
        Z = Z * sOld + t;                                                      \
        _Pragma("unroll")                                                      \
        for (int q = 0; q < 4; ++q) {                                          \
            acc[q].x = acc[q].x * sOld + t * FREG[q].x;                        \
            acc[q].y = acc[q].y * sOld + t * FREG[q].y;                        \
            acc[q].z = acc[q].z * sOld + t * FREG[q].z;                        \
            acc[q].w = acc[q].w * sOld + t * FREG[q].w;                        \
        }                                                                      \
        m = mn;                                                                \
    } while (0)

    for (int it = 0; it < 8; it += 2) {
        const int r0 = wslot + 512 * it;
        {   // prefetch next row
            const float4* f4 = (const float4*)(fc + (size_t)(r0 + 512) * DIM);
            #pragma unroll
            for (int q = 0; q < 4; ++q) fB[q] = f4[lane + 64*q];
        }
        K1_PROCESS(fA, r0);
        if (it + 2 < 8) {
            const float4* f4 = (const float4*)(fc + (size_t)(r0 + 1024) * DIM);
            #pragma unroll
            for (int q = 0; q < 4; ++q) fA[q] = f4[lane + 64*q];
        }
        K1_PROCESS(fB, r0 + 512);
    }
    #undef K1_PROCESS

    __shared__ float sm[4], sz[4];
    __shared__ float sacc[4][DIM];
    if (lane == 0) { sm[wave] = m; sz[wave] = Z; }
    #pragma unroll
    for (int q = 0; q < 4; ++q)
        ((float4*)sacc[wave])[lane + 64*q] = acc[q];
    __syncthreads();

    const float mb = fmaxf(fmaxf(sm[0], sm[1]), fmaxf(sm[2], sm[3]));
    const float e0 = __expf(sm[0] - mb), e1 = __expf(sm[1] - mb);
    const float e2 = __expf(sm[2] - mb), e3 = __expf(sm[3] - mb);
    float4 a0 = ((float4*)sacc[0])[tid];
    float4 a1 = ((float4*)sacc[1])[tid];
    float4 a2 = ((float4*)sacc[2])[tid];
    float4 a3 = ((float4*)sacc[3])[tid];
    float4 o;
    o.x = a0.x*e0 + a1.x*e1 + a2.x*e2 + a3.x*e3;
    o.y = a0.y*e0 + a1.y*e1 + a2.y*e2 + a3.y*e3;
    o.z = a0.z*e0 + a1.z*e1 + a2.z*e2 + a3.z*e3;
    o.w = a0.w*e0 + a1.w*e1 + a2.w*e2 + a3.w*e3;
    ((float4*)(pacc + (size_t)(c * K1B + blk) * DIM))[tid] = o;
    if (tid == 0) {
        pm[c * K1B + blk] = mb;
        pz[c * K1B + blk] = sz[0]*e0 + sz[1]*e1 + sz[2]*e2 + sz[3]*e3;
    }
}

// ---------------- K2: combine block partials -> g_c = A^T feats ----------------
// grid (4 j-chunks, NC), 256 threads = 64 float4-slots x 4 b-groups.
__global__ __launch_bounds__(256) void k2_combine(
    const float* __restrict__ pacc, const float* __restrict__ pm,
    const float* __restrict__ pz, float* __restrict__ g)  // (8,1024)
{
    const int c = blockIdx.y, jb = blockIdx.x;
    const int tid  = threadIdx.x;
    const int slot = tid & 63;
    const int bg   = tid >> 6;         // 0..3, each handles 32 partials
    __shared__ float spm[K1B], spz[K1B], swe[K1B];
    __shared__ float szc;
    __shared__ float4 sred[3][64];

    if (tid < K1B) spm[tid] = pm[c*K1B + tid];
    else spz[tid - K1B] = pz[c*K1B + tid - K1B];
    __syncthreads();
    float mc = -INFINITY;
    for (int b = 0; b < K1B; ++b) mc = fmaxf(mc, spm[b]);
    if (tid < K1B) swe[tid] = __expf(spm[tid] - mc);
    __syncthreads();
    if (tid == 0) {
        float z = 0.f;
        for (int b = 0; b < K1B; ++b) z += spz[b] * swe[b];
        szc = z;
    }

    const int jbase = jb * 256 + slot * 4;
    float4 a = make_float4(0.f, 0.f, 0.f, 0.f);
    #pragma unroll
    for (int k = 0; k < 32; ++k) {
        const int b = bg * 32 + k;
        const float e = swe[b];
        float4 v = *(const float4*)(pacc + (size_t)(c*K1B + b) * DIM + jbase);
        a.x += e*v.x; a.y += e*v.y; a.z += e*v.z; a.w += e*v.w;
    }
    if (bg) sred[bg-1][slot] = a;
    __syncthreads();
    if (bg == 0) {
        float4 t0 = sred[0][slot], t1 = sred[1][slot], t2 = sred[2][slot];
        const float inv = 1.0f / szc;
        float4 o;
        o.x = (a.x + t0.x + t1.x + t2.x) * inv;
        o.y = (a.y + t0.y + t1.y + t2.y) * inv;
        o.z = (a.z + t0.z + t1.z + t2.z) * inv;
        o.w = (a.w + t0.w + t1.w + t2.w) * inv;
        *(float4*)(g + c * DIM + jbase) = o;
    }
}

// ---------------- K3a: partial rank counts, register-blocked ----------------
__global__ __launch_bounds__(256) void k3a_rank(
    const u64* __restrict__ keys, int* __restrict__ part) // part (8 js,8 c,4096)
{
    const int iblk = blockIdx.x, js = blockIdx.y, c = blockIdx.z;
    const int tid = threadIdx.x;
    __shared__ u64 lk[512];
    ((float4*)lk)[tid] = ((const float4*)(keys + c * NPER + js * 512))[tid];

    const int ibase = iblk * 1024;
    u64 ki[4];
    #pragma unroll
    for (int q = 0; q < 4; ++q) ki[q] = keys[c * NPER + ibase + tid + 256*q];
    __syncthreads();

    int cnt0 = 0, cnt1 = 0, cnt2 = 0, cnt3 = 0;
    const ull2* lk2 = (const ull2*)lk;
    #pragma unroll 4
    for (int jt = 0; jt < 256; ++jt) {
        ull2 kj = lk2[jt];              // wave-uniform broadcast, conflict-free
        cnt0 += (kj.x > ki[0]) + (kj.y > ki[0]);
        cnt1 += (kj.x > ki[1]) + (kj.y > ki[1]);
        cnt2 += (kj.x > ki[2]) + (kj.y > ki[2]);
        cnt3 += (kj.x > ki[3]) + (kj.y > ki[3]);
    }
    int* dst = part + ((js * NC + c) << 12) + ibase + tid;
    dst[0]   = cnt0; dst[256] = cnt1; dst[512] = cnt2; dst[768] = cnt3;
}

// ---------------- K3b: sum partial ranks, scatter selected indices ----------------
__global__ __launch_bounds__(256) void k3b_scatter(
    const int* __restrict__ part, int* __restrict__ sel)  // sel (8,128)
{
    const int c = blockIdx.y;
    const int i = blockIdx.x * 256 + threadIdx.x;
    int r = 0;
    #pragma unroll
    for (int js = 0; js < 8; ++js) r += part[((js * NC + c) << 12) + i];
    if (r < TOPK) sel[c * TOPK + r] = i;
}

// ---------------- K4: gather selected rows (exact fp32 copies) ----------------
__global__ __launch_bounds__(256) void k4_gather(
    const float* __restrict__ feats, const int* __restrict__ sel,
    float* __restrict__ out_sel)
{
    const int b = blockIdx.x;          // 0..1023
    const int c = b >> 7;
    const int i = sel[b];
    const float4* src = (const float4*)(feats + ((size_t)c * NPER + i) * DIM);
    float4* dst = (float4*)(out_sel + (size_t)b * DIM);
    dst[threadIdx.x] = src[threadIdx.x];
}

// ---------------- K5: fus = v_w @ g + v_b, all clusters in one pass over v_w ----
// grid (128), 256 threads; g (8,1024) staged in LDS; wave handles 2 rows x 8 clusters.
__global__ __launch_bounds__(256) void k5_fusion(
    const float* __restrict__ v_w, const float* __restrict__ v_b,
    const float* __restrict__ g, float* __restrict__ fus)
{
    __shared__ float4 sg[NC][256];     // 32 KB
    const int tid = threadIdx.x, lane = tid & 63, wave = tid >> 6;
    for (int t = tid; t < NC * 256; t += 256)
        ((float4*)sg)[t] = ((const float4*)g)[t];
    __syncthreads();

    const int row0 = blockIdx.x * 8 + wave * 2;
    for (int rr = 0; rr < 2; ++rr) {
        const int o = row0 + rr;
        const float4* vr = (const float4*)(v_w + (size_t)o * DIM);
        float4 v[4];
        #pragma unroll
        for (int u = 0; u < 4; ++u) v[u] = vr[lane + 64*u];
        float p[NC];
        #pragma unroll
        for (int cc = 0; cc < NC; ++cc) {
            float s = 0.f;
            #pragma unroll
            for (int u = 0; u < 4; ++u) {
                float4 gv = sg[cc][lane + 64*u];
                s += v[u].x*gv.x + v[u].y*gv.y + v[u].z*gv.z + v[u].w*gv.w;
            }
            p[cc] = s;
        }
        #pragma unroll
        for (int off = 32; off > 0; off >>= 1) {
            #pragma unroll
            for (int cc = 0; cc < NC; ++cc) p[cc] += __shfl_xor(p[cc], off, 64);
        }
        if (lane == 0) {
            const float b = v_b[o];
            #pragma unroll
            for (int cc = 0; cc < NC; ++cc) fus[cc * DIM + o] = p[cc] + b;
        }
    }
}

extern "C" void kernel_launch(void* const* d_in, const int* in_sizes, int n_in,
                              void* d_out, int out_size, void* d_ws, size_t ws_size,
                              hipStream_t stream) {
    const float* feats     = (const float*)d_in[0];
    const float* key_feats = (const float*)d_in[1];
    const float* q_w       = (const float*)d_in[2];
    const float* q_b       = (const float*)d_in[3];
    const float* v_w       = (const float*)d_in[4];
    const float* v_b       = (const float*)d_in[5];
    float* out      = (float*)d_out;
    float* out_sel  = out;
    float* out_fus  = out + (size_t)1024 * 1024;

    // workspace layout (8B-aligned first)
    u64*   keys   = (u64*)d_ws;                          // 256 KB
    float* pacc   = (float*)(keys + NC * NPER);          // 8*128*1024 f = 4 MB
    float* pm     = pacc + (size_t)NC * K1B * DIM;       // 1024
    float* pz     = pm + NC * K1B;                       // 1024
    float* g      = pz + NC * K1B;                       // 8*1024
    float* w_all  = g + NC * DIM;                        // 8*1024
    int*   part   = (int*)(w_all + NC * DIM);            // 8*8*4096 = 1 MB
    int*   sel    = part + 8 * NC * NPER;                // 1024

    k0_prep    <<<dim3(NC * 4),    256, 0, stream>>>(key_feats, q_w, q_b, w_all);
    k1_main    <<<dim3(K1B, NC),   256, 0, stream>>>(feats, w_all, keys, pacc, pm, pz);
    k2_combine <<<dim3(4, NC),     256, 0, stream>>>(pacc, pm, pz, g);
    k3a_rank   <<<dim3(4, 8, NC),  256, 0, stream>>>(keys, part);
    k3b_scatter<<<dim3(16, NC),    256, 0, stream>>>(part, sel);
    k4_gather  <<<dim3(NC * TOPK), 256, 0, stream>>>(feats, sel, out_sel);
    k5_fusion  <<<dim3(128),       256, 0, stream>>>(v_w, v_b, g, out_fus);
}

// Round 4
// 257.317 us; speedup vs baseline: 1.0692x; 1.0692x over previous
//
#include <hip/hip_runtime.h>
#include <math.h>

// AdaptiveSelection on MI355X (gfx950)
// Inputs (fp32): cluster_features (8,4096,1024), key_feats (8,1,1024),
//                q_w (128,1024), q_b (128), v_w (1024,1024), v_b (1024)
// Outputs (fp32, concat): selected (1024,1024) then fus (8,1024)
//
// Algebra:
//   logit_i = f_i . w_c where w_c = q_w^T (q_w key_c + q_b)/sqrt(128) (+const, dropped)
//   topk-128 by logit == topk by softmax (monotone)
//   fusion = v_w @ (A^T feats) + v_b     (sum A = 1)
// Ranking: 64-bit sortable key (ordered float bits << 32 | ~index) makes the
// reference's (value desc, index asc) order a single unsigned compare.

#define DIM   1024
#define NC    8
#define NPER  4096
#define QD    128
#define TOPK  128
#define K1B   128     // blocks per cluster in main streaming pass (4 blocks/CU)

typedef unsigned long long u64;
typedef __attribute__((ext_vector_type(2))) unsigned long long ull2;

// ---------------- K0: fused prep -> w_all (8,1024) ----------------
__global__ __launch_bounds__(256) void k0_prep(
    const float* __restrict__ key_feats, const float* __restrict__ q_w,
    const float* __restrict__ q_b, float* __restrict__ w_all)
{
    const int c  = blockIdx.x >> 2, jc = blockIdx.x & 3;
    const int tid = threadIdx.x;
    __shared__ float part[256];
    __shared__ float qs[QD];

    {   // phase 1: qk[k] = dot(q_w[k], key_c) + q_b[k]; 2 threads per k
        const int k = tid >> 1, half = tid & 1;
        const float4* qr4 = (const float4*)(q_w + (size_t)k * DIM + half * 512);
        const float4* kf4 = (const float4*)(key_feats + (size_t)c * DIM + half * 512);
        float s = 0.f;
        #pragma unroll 16
        for (int j = 0; j < 128; ++j) {
            float4 a = qr4[j], b = kf4[j];
            s += a.x*b.x + a.y*b.y + a.z*b.z + a.w*b.w;
        }
        part[tid] = s;
    }
    __syncthreads();
    if (tid < QD) qs[tid] = part[2*tid] + part[2*tid+1] + q_b[tid];
    __syncthreads();

    // phase 2: w[j] = sum_k q_w[k][j] * qk[k] / sqrt(128)
    const int j = jc * 256 + tid;
    float s = 0.f;
    #pragma unroll 16
    for (int k = 0; k < QD; ++k)
        s += q_w[(size_t)k * DIM + j] * qs[k];
    w_all[c * DIM + j] = s * 0.08838834764831845f; // 1/sqrt(128)
}

// ---------------- K1: fused logits(keys) + online-softmax weighted row sum ----------
// grid (K1B, NC), block 256 = 4 waves; one wave per row; 8 rows/wave; dbuf prefetch.
// Rescale branch is wave-uniform (p uniform after butterfly); rare after warmup.
__global__ __launch_bounds__(256, 4) void k1_main(
    const float* __restrict__ feats, const float* __restrict__ w_all,
    u64* __restrict__ keys,            // (8,4096) sortable keys
    float* __restrict__ pacc,          // (8*K1B,1024)
    float* __restrict__ pm, float* __restrict__ pz)  // (8*K1B)
{
    const int c    = blockIdx.y;
    const int blk  = blockIdx.x;
    const int tid  = threadIdx.x;
    const int lane = tid & 63;
    const int wave = tid >> 6;

    const float4* w4 = (const float4*)(w_all + c * DIM);
    float4 wv[4];
    #pragma unroll
    for (int q = 0; q < 4; ++q) wv[q] = w4[lane + 64*q];

    float4 acc[4];
    #pragma unroll
    for (int q = 0; q < 4; ++q) acc[q] = make_float4(0.f, 0.f, 0.f, 0.f);
    float m = -INFINITY, Z = 0.f;

    const int wslot = blk * 4 + wave;          // 0..511
    const float* fc = feats + (size_t)c * NPER * DIM;

    float4 fA[4], fB[4];
    {
        const float4* f4 = (const float4*)(fc + (size_t)wslot * DIM);
        #pragma unroll
        for (int q = 0; q < 4; ++q) fA[q] = f4[lane + 64*q];
    }

    #define K1_PROCESS(FREG, ROW)                                              \
    do {                                                                       \
        float p = 0.f;                                                         \
        _Pragma("unroll")                                                      \
        for (int q = 0; q < 4; ++q)                                            \
            p += FREG[q].x*wv[q].x + FREG[q].y*wv[q].y +                       \
                 FREG[q].z*wv[q].z + FREG[q].w*wv[q].w;                        \
        _Pragma("unroll")                                                      \
        for (int off = 32; off > 0; off >>= 1) p += __shfl_xor(p, off, 64);    \
        if (lane == 0) {                                                       \
            unsigned int b = __float_as_uint(p);                               \
            unsigned int u = b ^ ((b & 0x80000000u) ? 0xFFFFFFFFu : 0x80000000u); \
            keys[c * NPER + (ROW)] = ((u64)u << 32) | (unsigned int)(~(ROW));  \
        }                                                                      \
        if (p > m) {   /* wave-uniform; rare after first rows */               \
            const float sOld = __expf(m - p);                                  \
            Z = Z * sOld + 1.f;                                                \
            _Pragma("unroll")                                                  \
            for (int q = 0; q < 4; ++q) {                                      \
                acc[q].x = acc[q].x * sOld + FREG[q].x;                        \
                acc[q].y = acc[q].y * sOld + FREG[q].y;                        \
                acc[q].z = acc[q].z * sOld + FREG[q].z;                        \
                acc[q].w = acc[q].w * sOld + FREG[q].w;                        \
            }                                                                  \
            m = p;                                                             \
        } else {                                                               \
            const float t = __expf(p - m);                                     \
            Z += t;                                                            \
            _Pragma("unroll")                                                  \
            for (int q = 0; q < 4; ++q) {                                      \
                acc[q].x += t * FREG[q].x;                                     \
                acc[q].y += t * FREG[q].y;                                     \
                acc[q].z += t * FREG[q].z;                                     \
                acc[q].w += t * FREG[q].w;                                     \
            }                                                                  \
        }                                                                      \
    } while (0)

    for (int it = 0; it < 8; it += 2) {
        const int r0 = wslot + 512 * it;
        {   // prefetch next row
            const float4* f4 = (const float4*)(fc + (size_t)(r0 + 512) * DIM);
            #pragma unroll
            for (int q = 0; q < 4; ++q) fB[q] = f4[lane + 64*q];
        }
        K1_PROCESS(fA, r0);
        if (it + 2 < 8) {
            const float4* f4 = (const float4*)(fc + (size_t)(r0 + 1024) * DIM);
            #pragma unroll
            for (int q = 0; q < 4; ++q) fA[q] = f4[lane + 64*q];
        }
        K1_PROCESS(fB, r0 + 512);
    }
    #undef K1_PROCESS

    __shared__ float sm[4], sz[4];
    __shared__ float sacc[4][DIM];
    if (lane == 0) { sm[wave] = m; sz[wave] = Z; }
    #pragma unroll
    for (int q = 0; q < 4; ++q)
        ((float4*)sacc[wave])[lane + 64*q] = acc[q];
    __syncthreads();

    const float mb = fmaxf(fmaxf(sm[0], sm[1]), fmaxf(sm[2], sm[3]));
    const float e0 = __expf(sm[0] - mb), e1 = __expf(sm[1] - mb);
    const float e2 = __expf(sm[2] - mb), e3 = __expf(sm[3] - mb);
    float4 a0 = ((float4*)sacc[0])[tid];
    float4 a1 = ((float4*)sacc[1])[tid];
    float4 a2 = ((float4*)sacc[2])[tid];
    float4 a3 = ((float4*)sacc[3])[tid];
    float4 o;
    o.x = a0.x*e0 + a1.x*e1 + a2.x*e2 + a3.x*e3;
    o.y = a0.y*e0 + a1.y*e1 + a2.y*e2 + a3.y*e3;
    o.z = a0.z*e0 + a1.z*e1 + a2.z*e2 + a3.z*e3;
    o.w = a0.w*e0 + a1.w*e1 + a2.w*e2 + a3.w*e3;
    ((float4*)(pacc + (size_t)(c * K1B + blk) * DIM))[tid] = o;
    if (tid == 0) {
        pm[c * K1B + blk] = mb;
        pz[c * K1B + blk] = sz[0]*e0 + sz[1]*e1 + sz[2]*e2 + sz[3]*e3;
    }
}

// ---------------- K2: combine block partials -> g_c = A^T feats ----------------
__global__ __launch_bounds__(256) void k2_combine(
    const float* __restrict__ pacc, const float* __restrict__ pm,
    const float* __restrict__ pz, float* __restrict__ g)  // (8,1024)
{
    const int c = blockIdx.y, jb = blockIdx.x;
    const int tid  = threadIdx.x;
    const int slot = tid & 63;
    const int bg   = tid >> 6;         // 0..3, each handles 32 partials
    __shared__ float spm[K1B], spz[K1B], swe[K1B];
    __shared__ float szc;
    __shared__ float4 sred[3][64];

    if (tid < K1B) spm[tid] = pm[c*K1B + tid];
    else spz[tid - K1B] = pz[c*K1B + tid - K1B];
    __syncthreads();
    float mc = -INFINITY;
    for (int b = 0; b < K1B; ++b) mc = fmaxf(mc, spm[b]);
    if (tid < K1B) swe[tid] = __expf(spm[tid] - mc);
    __syncthreads();
    if (tid == 0) {
        float z = 0.f;
        for (int b = 0; b < K1B; ++b) z += spz[b] * swe[b];
        szc = z;
    }

    const int jbase = jb * 256 + slot * 4;
    float4 a = make_float4(0.f, 0.f, 0.f, 0.f);
    #pragma unroll
    for (int k = 0; k < 32; ++k) {
        const int b = bg * 32 + k;
        const float e = swe[b];
        float4 v = *(const float4*)(pacc + (size_t)(c*K1B + b) * DIM + jbase);
        a.x += e*v.x; a.y += e*v.y; a.z += e*v.z; a.w += e*v.w;
    }
    if (bg) sred[bg-1][slot] = a;
    __syncthreads();
    if (bg == 0) {
        float4 t0 = sred[0][slot], t1 = sred[1][slot], t2 = sred[2][slot];
        const float inv = 1.0f / szc;
        float4 o;
        o.x = (a.x + t0.x + t1.x + t2.x) * inv;
        o.y = (a.y + t0.y + t1.y + t2.y) * inv;
        o.z = (a.z + t0.z + t1.z + t2.z) * inv;
        o.w = (a.w + t0.w + t1.w + t2.w) * inv;
        *(float4*)(g + c * DIM + jbase) = o;
    }
}

// ---------------- K3a: partial rank counts, register-blocked ----------------
__global__ __launch_bounds__(256) void k3a_rank(
    const u64* __restrict__ keys, int* __restrict__ part) // part (8 js,8 c,4096)
{
    const int iblk = blockIdx.x, js = blockIdx.y, c = blockIdx.z;
    const int tid = threadIdx.x;
    __shared__ u64 lk[512];
    ((float4*)lk)[tid] = ((const float4*)(keys + c * NPER + js * 512))[tid];

    const int ibase = iblk * 1024;
    u64 ki[4];
    #pragma unroll
    for (int q = 0; q < 4; ++q) ki[q] = keys[c * NPER + ibase + tid + 256*q];
    __syncthreads();

    int cnt0 = 0, cnt1 = 0, cnt2 = 0, cnt3 = 0;
    const ull2* lk2 = (const ull2*)lk;
    #pragma unroll 4
    for (int jt = 0; jt < 256; ++jt) {
        ull2 kj = lk2[jt];              // wave-uniform broadcast, conflict-free
        cnt0 += (kj.x > ki[0]) + (kj.y > ki[0]);
        cnt1 += (kj.x > ki[1]) + (kj.y > ki[1]);
        cnt2 += (kj.x > ki[2]) + (kj.y > ki[2]);
        cnt3 += (kj.x > ki[3]) + (kj.y > ki[3]);
    }
    int* dst = part + ((js * NC + c) << 12) + ibase + tid;
    dst[0]   = cnt0; dst[256] = cnt1; dst[512] = cnt2; dst[768] = cnt3;
}

// ---------------- K3b: sum ranks + gather selected rows (fused) ----------------
// grid (16, NC), 256 threads: thread handles one i; selected (i,r) go to an LDS
// worklist; block then cooperatively copies each selected row (1 float4/thread).
__global__ __launch_bounds__(256) void k3b_gather(
    const int* __restrict__ part, const float* __restrict__ feats,
    float* __restrict__ out_sel)
{
    const int c = blockIdx.y;
    const int i = blockIdx.x * 256 + threadIdx.x;
    const int tid = threadIdx.x;
    __shared__ int list_i[TOPK], list_r[TOPK];
    __shared__ int cnt;
    if (tid == 0) cnt = 0;
    __syncthreads();

    int r = 0;
    #pragma unroll
    for (int js = 0; js < 8; ++js) r += part[((js * NC + c) << 12) + i];
    if (r < TOPK) {
        const int s = atomicAdd(&cnt, 1);
        list_i[s] = i; list_r[s] = r;
    }
    __syncthreads();

    const int n = cnt;
    for (int s = 0; s < n; ++s) {
        const float4* src = (const float4*)(feats + ((size_t)c * NPER + list_i[s]) * DIM);
        float4* dst = (float4*)(out_sel + ((size_t)c * TOPK + list_r[s]) * DIM);
        dst[tid] = src[tid];
    }
}

// ---------------- K5: fus = v_w @ g + v_b, all clusters in one pass over v_w ----
__global__ __launch_bounds__(256) void k5_fusion(
    const float* __restrict__ v_w, const float* __restrict__ v_b,
    const float* __restrict__ g, float* __restrict__ fus)
{
    __shared__ float4 sg[NC][256];     // 32 KB
    const int tid = threadIdx.x, lane = tid & 63, wave = tid >> 6;
    for (int t = tid; t < NC * 256; t += 256)
        ((float4*)sg)[t] = ((const float4*)g)[t];
    __syncthreads();

    const int row0 = blockIdx.x * 8 + wave * 2;
    for (int rr = 0; rr < 2; ++rr) {
        const int o = row0 + rr;
        const float4* vr = (const float4*)(v_w + (size_t)o * DIM);
        float4 v[4];
        #pragma unroll
        for (int u = 0; u < 4; ++u) v[u] = vr[lane + 64*u];
        float p[NC];
        #pragma unroll
        for (int cc = 0; cc < NC; ++cc) {
            float s = 0.f;
            #pragma unroll
            for (int u = 0; u < 4; ++u) {
                float4 gv = sg[cc][lane + 64*u];
                s += v[u].x*gv.x + v[u].y*gv.y + v[u].z*gv.z + v[u].w*gv.w;
            }
            p[cc] = s;
        }
        #pragma unroll
        for (int off = 32; off > 0; off >>= 1) {
            #pragma unroll
            for (int cc = 0; cc < NC; ++cc) p[cc] += __shfl_xor(p[cc], off, 64);
        }
        if (lane == 0) {
            const float b = v_b[o];
            #pragma unroll
            for (int cc = 0; cc < NC; ++cc) fus[cc * DIM + o] = p[cc] + b;
        }
    }
}

extern "C" void kernel_launch(void* const* d_in, const int* in_sizes, int n_in,
                              void* d_out, int out_size, void* d_ws, size_t ws_size,
                              hipStream_t stream) {
    const float* feats     = (const float*)d_in[0];
    const float* key_feats = (const float*)d_in[1];
    const float* q_w       = (const float*)d_in[2];
    const float* q_b       = (const float*)d_in[3];
    const float* v_w       = (const float*)d_in[4];
    const float* v_b       = (const float*)d_in[5];
    float* out      = (float*)d_out;
    float* out_sel  = out;
    float* out_fus  = out + (size_t)1024 * 1024;

    // workspace layout (8B-aligned first)
    u64*   keys   = (u64*)d_ws;                          // 256 KB
    float* pacc   = (float*)(keys + NC * NPER);          // 4 MB
    float* pm     = pacc + (size_t)NC * K1B * DIM;       // 1024
    float* pz     = pm + NC * K1B;                       // 1024
    float* g      = pz + NC * K1B;                       // 8*1024
    float* w_all  = g + NC * DIM;                        // 8*1024
    int*   part   = (int*)(w_all + NC * DIM);            // 1 MB

    k0_prep    <<<dim3(NC * 4),    256, 0, stream>>>(key_feats, q_w, q_b, w_all);
    k1_main    <<<dim3(K1B, NC),   256, 0, stream>>>(feats, w_all, keys, pacc, pm, pz);
    k2_combine <<<dim3(4, NC),     256, 0, stream>>>(pacc, pm, pz, g);
    k3a_rank   <<<dim3(4, 8, NC),  256, 0, stream>>>(keys, part);
    k3b_gather <<<dim3(16, NC),    256, 0, stream>>>(part, feats, out_sel);
    k5_fusion  <<<dim3(128),       256, 0, stream>>>(v_w, v_b, g, out_fus);
}

// Round 5
// 246.051 us; speedup vs baseline: 1.1182x; 1.0458x over previous
//
#include <hip/hip_runtime.h>
#include <math.h>

// AdaptiveSelection on MI355X (gfx950)
// Inputs (fp32): cluster_features (8,4096,1024), key_feats (8,1,1024),
//                q_w (128,1024), q_b (128), v_w (1024,1024), v_b (1024)
// Outputs (fp32, concat): selected (1024,1024) then fus (8,1024)
//
// Algebra:
//   logit_i = f_i . w_c where w_c = q_w^T (q_w key_c + q_b)/sqrt(128) (+const, dropped)
//   topk-128 by logit == topk by softmax (monotone)
//   fusion = v_w @ (A^T feats) + v_b     (sum A = 1)
// Ranking: 64-bit sortable key (ordered float bits << 32 | ~index) makes the
// reference's (value desc, index asc) order a single unsigned compare.
// 4 dispatches: k0 -> k1 -> fat(k2|k3a) -> fat(k3b|k5).

#define DIM   1024
#define NC    8
#define NPER  4096
#define QD    128
#define TOPK  128
#define K1B   128     // blocks per cluster in main streaming pass (4 blocks/CU)
#define JS    16      // j-slices in rank pass

typedef unsigned long long u64;
typedef __attribute__((ext_vector_type(2))) unsigned long long ull2;

// ---------------- K0: fused prep -> w_all (8,1024) ----------------
__global__ __launch_bounds__(256) void k0_prep(
    const float* __restrict__ key_feats, const float* __restrict__ q_w,
    const float* __restrict__ q_b, float* __restrict__ w_all)
{
    const int c  = blockIdx.x >> 2, jc = blockIdx.x & 3;
    const int tid = threadIdx.x;
    __shared__ float part[256];
    __shared__ float qs[QD];

    {   // phase 1: qk[k] = dot(q_w[k], key_c) + q_b[k]; 2 threads per k
        const int k = tid >> 1, half = tid & 1;
        const float4* qr4 = (const float4*)(q_w + (size_t)k * DIM + half * 512);
        const float4* kf4 = (const float4*)(key_feats + (size_t)c * DIM + half * 512);
        float s = 0.f;
        #pragma unroll 16
        for (int j = 0; j < 128; ++j) {
            float4 a = qr4[j], b = kf4[j];
            s += a.x*b.x + a.y*b.y + a.z*b.z + a.w*b.w;
        }
        part[tid] = s;
    }
    __syncthreads();
    if (tid < QD) qs[tid] = part[2*tid] + part[2*tid+1] + q_b[tid];
    __syncthreads();

    // phase 2: w[j] = sum_k q_w[k][j] * qk[k] / sqrt(128)
    const int j = jc * 256 + tid;
    float s = 0.f;
    #pragma unroll 16
    for (int k = 0; k < QD; ++k)
        s += q_w[(size_t)k * DIM + j] * qs[k];
    w_all[c * DIM + j] = s * 0.08838834764831845f; // 1/sqrt(128)
}

// ---------------- K1: fused logits(keys) + online-softmax weighted row sum ----------
__global__ __launch_bounds__(256, 4) void k1_main(
    const float* __restrict__ feats, const float* __restrict__ w_all,
    u64* __restrict__ keys,            // (8,4096) sortable keys
    float* __restrict__ pacc,          // (8*K1B,1024)
    float* __restrict__ pm, float* __restrict__ pz)  // (8*K1B)
{
    const int c    = blockIdx.y;
    const int blk  = blockIdx.x;
    const int tid  = threadIdx.x;
    const int lane = tid & 63;
    const int wave = tid >> 6;

    const float4* w4 = (const float4*)(w_all + c * DIM);
    float4 wv[4];
    #pragma unroll
    for (int q = 0; q < 4; ++q) wv[q] = w4[lane + 64*q];

    float4 acc[4];
    #pragma unroll
    for (int q = 0; q < 4; ++q) acc[q] = make_float4(0.f, 0.f, 0.f, 0.f);
    float m = -INFINITY, Z = 0.f;

    const int wslot = blk * 4 + wave;          // 0..511
    const float* fc = feats + (size_t)c * NPER * DIM;

    float4 fA[4], fB[4];
    {
        const float4* f4 = (const float4*)(fc + (size_t)wslot * DIM);
        #pragma unroll
        for (int q = 0; q < 4; ++q) fA[q] = f4[lane + 64*q];
    }

    #define K1_PROCESS(FREG, ROW)                                              \
    do {                                                                       \
        float p = 0.f;                                                         \
        _Pragma("unroll")                                                      \
        for (int q = 0; q < 4; ++q)                                            \
            p += FREG[q].x*wv[q].x + FREG[q].y*wv[q].y +                       \
                 FREG[q].z*wv[q].z + FREG[q].w*wv[q].w;                        \
        _Pragma("unroll")                                                      \
        for (int off = 32; off > 0; off >>= 1) p += __shfl_xor(p, off, 64);    \
        if (lane == 0) {                                                       \
            unsigned int b = __float_as_uint(p);                               \
            unsigned int u = b ^ ((b & 0x80000000u) ? 0xFFFFFFFFu : 0x80000000u); \
            keys[c * NPER + (ROW)] = ((u64)u << 32) | (unsigned int)(~(ROW));  \
        }                                                                      \
        if (p > m) {   /* wave-uniform; rare after first rows */               \
            const float sOld = __expf(m - p);                                  \
            Z = Z * sOld + 1.f;                                                \
            _Pragma("unroll")                                                  \
            for (int q = 0; q < 4; ++q) {                                      \
                acc[q].x = acc[q].x * sOld + FREG[q].x;                        \
                acc[q].y = acc[q].y * sOld + FREG[q].y;                        \
                acc[q].z = acc[q].z * sOld + FREG[q].z;                        \
                acc[q].w = acc[q].w * sOld + FREG[q].w;                        \
            }                                                                  \
            m = p;                                                             \
        } else {                                                               \
            const float t = __expf(p - m);                                     \
            Z += t;                                                            \
            _Pragma("unroll")                                                  \
            for (int q = 0; q < 4; ++q) {                                      \
                acc[q].x += t * FREG[q].x;                                     \
                acc[q].y += t * FREG[q].y;                                     \
                acc[q].z += t * FREG[q].z;                                     \
                acc[q].w += t * FREG[q].w;                                     \
            }                                                                  \
        }                                                                      \
    } while (0)

    for (int it = 0; it < 8; it += 2) {
        const int r0 = wslot + 512 * it;
        {   // prefetch next row
            const float4* f4 = (const float4*)(fc + (size_t)(r0 + 512) * DIM);
            #pragma unroll
            for (int q = 0; q < 4; ++q) fB[q] = f4[lane + 64*q];
        }
        K1_PROCESS(fA, r0);
        if (it + 2 < 8) {
            const float4* f4 = (const float4*)(fc + (size_t)(r0 + 1024) * DIM);
            #pragma unroll
            for (int q = 0; q < 4; ++q) fA[q] = f4[lane + 64*q];
        }
        K1_PROCESS(fB, r0 + 512);
    }
    #undef K1_PROCESS

    __shared__ float sm[4], sz[4];
    __shared__ float sacc[4][DIM];
    if (lane == 0) { sm[wave] = m; sz[wave] = Z; }
    #pragma unroll
    for (int q = 0; q < 4; ++q)
        ((float4*)sacc[wave])[lane + 64*q] = acc[q];
    __syncthreads();

    const float mb = fmaxf(fmaxf(sm[0], sm[1]), fmaxf(sm[2], sm[3]));
    const float e0 = __expf(sm[0] - mb), e1 = __expf(sm[1] - mb);
    const float e2 = __expf(sm[2] - mb), e3 = __expf(sm[3] - mb);
    float4 a0 = ((float4*)sacc[0])[tid];
    float4 a1 = ((float4*)sacc[1])[tid];
    float4 a2 = ((float4*)sacc[2])[tid];
    float4 a3 = ((float4*)sacc[3])[tid];
    float4 o;
    o.x = a0.x*e0 + a1.x*e1 + a2.x*e2 + a3.x*e3;
    o.y = a0.y*e0 + a1.y*e1 + a2.y*e2 + a3.y*e3;
    o.z = a0.z*e0 + a1.z*e1 + a2.z*e2 + a3.z*e3;
    o.w = a0.w*e0 + a1.w*e1 + a2.w*e2 + a3.w*e3;
    ((float4*)(pacc + (size_t)(c * K1B + blk) * DIM))[tid] = o;
    if (tid == 0) {
        pm[c * K1B + blk] = mb;
        pz[c * K1B + blk] = sz[0]*e0 + sz[1]*e1 + sz[2]*e2 + sz[3]*e3;
    }
}

// ---------------- FAT A: blocks 0..31 = k2_combine; 32..543 = k3a_rank ----------
__global__ __launch_bounds__(256) void fat_a(
    const float* __restrict__ pacc, const float* __restrict__ pm,
    const float* __restrict__ pz, float* __restrict__ g,
    const u64* __restrict__ keys, int* __restrict__ part) // part (JS,8c,4096)
{
    const int tid = threadIdx.x;
    if (blockIdx.x < 32) {
        // ---- k2: combine block partials -> g_c = A^T feats ----
        const int c = blockIdx.x >> 2, jb = blockIdx.x & 3;
        const int slot = tid & 63;
        const int bg   = tid >> 6;         // 0..3, each handles 32 partials
        __shared__ float spm[K1B], spz[K1B], swe[K1B];
        __shared__ float szc;
        __shared__ float4 sred[3][64];

        if (tid < K1B) spm[tid] = pm[c*K1B + tid];
        else spz[tid - K1B] = pz[c*K1B + tid - K1B];
        __syncthreads();
        float mc = -INFINITY;
        for (int b = 0; b < K1B; ++b) mc = fmaxf(mc, spm[b]);
        if (tid < K1B) swe[tid] = __expf(spm[tid] - mc);
        __syncthreads();
        if (tid == 0) {
            float z = 0.f;
            for (int b = 0; b < K1B; ++b) z += spz[b] * swe[b];
            szc = z;
        }

        const int jbase = jb * 256 + slot * 4;
        float4 a = make_float4(0.f, 0.f, 0.f, 0.f);
        #pragma unroll
        for (int k = 0; k < 32; ++k) {
            const int b = bg * 32 + k;
            const float e = swe[b];
            float4 v = *(const float4*)(pacc + (size_t)(c*K1B + b) * DIM + jbase);
            a.x += e*v.x; a.y += e*v.y; a.z += e*v.z; a.w += e*v.w;
        }
        if (bg) sred[bg-1][slot] = a;
        __syncthreads();
        if (bg == 0) {
            float4 t0 = sred[0][slot], t1 = sred[1][slot], t2 = sred[2][slot];
            const float inv = 1.0f / szc;
            float4 o;
            o.x = (a.x + t0.x + t1.x + t2.x) * inv;
            o.y = (a.y + t0.y + t1.y + t2.y) * inv;
            o.z = (a.z + t0.z + t1.z + t2.z) * inv;
            o.w = (a.w + t0.w + t1.w + t2.w) * inv;
            *(float4*)(g + c * DIM + jbase) = o;
        }
    } else {
        // ---- k3a: partial rank counts; grid 4 iblk x JS x 8 c ----
        const int t = blockIdx.x - 32;
        const int iblk = t & 3, js = (t >> 2) & (JS-1), c = t >> 6;
        __shared__ u64 lk[256];            // 256-key j-slice
        if (tid < 128)
            ((float4*)lk)[tid] = ((const float4*)(keys + c * NPER + js * 256))[tid];

        const int ibase = iblk * 1024;
        u64 ki[4];
        #pragma unroll
        for (int q = 0; q < 4; ++q) ki[q] = keys[c * NPER + ibase + tid + 256*q];
        __syncthreads();

        int cnt0 = 0, cnt1 = 0, cnt2 = 0, cnt3 = 0;
        const ull2* lk2 = (const ull2*)lk;
        #pragma unroll 4
        for (int jt = 0; jt < 128; ++jt) {
            ull2 kj = lk2[jt];             // wave-uniform broadcast, conflict-free
            cnt0 += (kj.x > ki[0]) + (kj.y > ki[0]);
            cnt1 += (kj.x > ki[1]) + (kj.y > ki[1]);
            cnt2 += (kj.x > ki[2]) + (kj.y > ki[2]);
            cnt3 += (kj.x > ki[3]) + (kj.y > ki[3]);
        }
        int* dst = part + ((js * NC + c) << 12) + ibase + tid;
        dst[0]   = cnt0; dst[256] = cnt1; dst[512] = cnt2; dst[768] = cnt3;
    }
}

// ---------------- FAT B: blocks 0..127 = k3b_gather; 128..255 = k5_fusion ------
__global__ __launch_bounds__(256) void fat_b(
    const int* __restrict__ part, const float* __restrict__ feats,
    float* __restrict__ out_sel,
    const float* __restrict__ v_w, const float* __restrict__ v_b,
    const float* __restrict__ g, float* __restrict__ fus)
{
    const int tid = threadIdx.x;
    if (blockIdx.x < 128) {
        // ---- k3b: sum ranks + gather selected rows ----
        const int c = blockIdx.x >> 4;
        const int i = (blockIdx.x & 15) * 256 + tid;
        __shared__ int list_i[TOPK], list_r[TOPK];
        __shared__ int cnt;
        if (tid == 0) cnt = 0;
        __syncthreads();

        int r = 0;
        #pragma unroll
        for (int js = 0; js < JS; ++js) r += part[((js * NC + c) << 12) + i];
        if (r < TOPK) {
            const int s = atomicAdd(&cnt, 1);
            list_i[s] = i; list_r[s] = r;
        }
        __syncthreads();

        const int n = cnt;
        for (int s = 0; s < n; ++s) {
            const float4* src = (const float4*)(feats + ((size_t)c * NPER + list_i[s]) * DIM);
            float4* dst = (float4*)(out_sel + ((size_t)c * TOPK + list_r[s]) * DIM);
            dst[tid] = src[tid];
        }
    } else {
        // ---- k5: fus = v_w @ g + v_b, one pass over v_w ----
        __shared__ float4 sg[NC][256];     // 32 KB
        const int lane = tid & 63, wave = tid >> 6;
        for (int t = tid; t < NC * 256; t += 256)
            ((float4*)sg)[t] = ((const float4*)g)[t];
        __syncthreads();

        const int row0 = (blockIdx.x - 128) * 8 + wave * 2;
        for (int rr = 0; rr < 2; ++rr) {
            const int o = row0 + rr;
            const float4* vr = (const float4*)(v_w + (size_t)o * DIM);
            float4 v[4];
            #pragma unroll
            for (int u = 0; u < 4; ++u) v[u] = vr[lane + 64*u];
            float p[NC];
            #pragma unroll
            for (int cc = 0; cc < NC; ++cc) {
                float s = 0.f;
                #pragma unroll
                for (int u = 0; u < 4; ++u) {
                    float4 gv = sg[cc][lane + 64*u];
                    s += v[u].x*gv.x + v[u].y*gv.y + v[u].z*gv.z + v[u].w*gv.w;
                }
                p[cc] = s;
            }
            #pragma unroll
            for (int off = 32; off > 0; off >>= 1) {
                #pragma unroll
                for (int cc = 0; cc < NC; ++cc) p[cc] += __shfl_xor(p[cc], off, 64);
            }
            if (lane == 0) {
                const float b = v_b[o];
                #pragma unroll
                for (int cc = 0; cc < NC; ++cc) fus[cc * DIM + o] = p[cc] + b;
            }
        }
    }
}

extern "C" void kernel_launch(void* const* d_in, const int* in_sizes, int n_in,
                              void* d_out, int out_size, void* d_ws, size_t ws_size,
                              hipStream_t stream) {
    const float* feats     = (const float*)d_in[0];
    const float* key_feats = (const float*)d_in[1];
    const float* q_w       = (const float*)d_in[2];
    const float* q_b       = (const float*)d_in[3];
    const float* v_w       = (const float*)d_in[4];
    const float* v_b       = (const float*)d_in[5];
    float* out      = (float*)d_out;
    float* out_sel  = out;
    float* out_fus  = out + (size_t)1024 * 1024;

    // workspace layout (8B-aligned first)
    u64*   keys   = (u64*)d_ws;                          // 256 KB
    float* pacc   = (float*)(keys + NC * NPER);          // 4 MB
    float* pm     = pacc + (size_t)NC * K1B * DIM;       // 1024
    float* pz     = pm + NC * K1B;                       // 1024
    float* g      = pz + NC * K1B;                       // 8*1024
    float* w_all  = g + NC * DIM;                        // 8*1024
    int*   part   = (int*)(w_all + NC * DIM);            // JS*8*4096 ints = 2 MB

    k0_prep <<<dim3(NC * 4),       256, 0, stream>>>(key_feats, q_w, q_b, w_all);
    k1_main <<<dim3(K1B, NC),      256, 0, stream>>>(feats, w_all, keys, pacc, pm, pz);
    fat_a   <<<dim3(32 + 4*JS*NC), 256, 0, stream>>>(pacc, pm, pz, g, keys, part);
    fat_b   <<<dim3(256),          256, 0, stream>>>(part, feats, out_sel, v_w, v_b, g, out_fus);
}

// Round 6
// 244.307 us; speedup vs baseline: 1.1262x; 1.0071x over previous
//
#include <hip/hip_runtime.h>
#include <math.h>

// AdaptiveSelection on MI355X (gfx950)
// Inputs (fp32): cluster_features (8,4096,1024), key_feats (8,1,1024),
//                q_w (128,1024), q_b (128), v_w (1024,1024), v_b (1024)
// Outputs (fp32, concat): selected (1024,1024) then fus (8,1024)
//
// Algebra:
//   logit_i = f_i . w_c where w_c = q_w^T (q_w key_c + q_b)/sqrt(128) (+const, dropped)
//   topk-128 by logit == topk by softmax (monotone)
//   fusion = v_w @ (A^T feats) + v_b     (sum A = 1)
// Ranking: 64-bit sortable key (ordered float bits << 32 | ~index) makes the
// reference's (value desc, index asc) order a single unsigned compare.
// 4 dispatches: k0 -> k1 -> fat(k2|k3a) -> fat(k3b|k5).

#define DIM   1024
#define NC    8
#define NPER  4096
#define QD    128
#define TOPK  128
#define K1B   128     // blocks per cluster in main streaming pass (4 blocks/CU)
#define JS    16      // j-slices in rank pass

typedef unsigned long long u64;
typedef __attribute__((ext_vector_type(2))) unsigned long long ull2;
typedef __attribute__((ext_vector_type(4))) float f4;   // for nontemporal loads

// ---------------- K0: fused prep -> w_all (8,1024) ----------------
__global__ __launch_bounds__(256) void k0_prep(
    const float* __restrict__ key_feats, const float* __restrict__ q_w,
    const float* __restrict__ q_b, float* __restrict__ w_all)
{
    const int c  = blockIdx.x >> 2, jc = blockIdx.x & 3;
    const int tid = threadIdx.x;
    __shared__ float part[256];
    __shared__ float qs[QD];

    {   // phase 1: qk[k] = dot(q_w[k], key_c) + q_b[k]; 2 threads per k
        const int k = tid >> 1, half = tid & 1;
        const float4* qr4 = (const float4*)(q_w + (size_t)k * DIM + half * 512);
        const float4* kf4 = (const float4*)(key_feats + (size_t)c * DIM + half * 512);
        float s = 0.f;
        #pragma unroll 16
        for (int j = 0; j < 128; ++j) {
            float4 a = qr4[j], b = kf4[j];
            s += a.x*b.x + a.y*b.y + a.z*b.z + a.w*b.w;
        }
        part[tid] = s;
    }
    __syncthreads();
    if (tid < QD) qs[tid] = part[2*tid] + part[2*tid+1] + q_b[tid];
    __syncthreads();

    // phase 2: w[j] = sum_k q_w[k][j] * qk[k] / sqrt(128)
    const int j = jc * 256 + tid;
    float s = 0.f;
    #pragma unroll 16
    for (int k = 0; k < QD; ++k)
        s += q_w[(size_t)k * DIM + j] * qs[k];
    w_all[c * DIM + j] = s * 0.08838834764831845f; // 1/sqrt(128)
}

// ---------------- K1: fused logits(keys) + online-softmax weighted row sum ----------
// feats stream via nontemporal loads (read-once; keep L2 for pacc/keys).
__global__ __launch_bounds__(256, 4) void k1_main(
    const float* __restrict__ feats, const float* __restrict__ w_all,
    u64* __restrict__ keys,            // (8,4096) sortable keys
    float* __restrict__ pacc,          // (8*K1B,1024)
    float* __restrict__ pm, float* __restrict__ pz)  // (8*K1B)
{
    const int c    = blockIdx.y;
    const int blk  = blockIdx.x;
    const int tid  = threadIdx.x;
    const int lane = tid & 63;
    const int wave = tid >> 6;

    const float4* w4 = (const float4*)(w_all + c * DIM);
    float4 wv[4];
    #pragma unroll
    for (int q = 0; q < 4; ++q) wv[q] = w4[lane + 64*q];

    float4 acc[4];
    #pragma unroll
    for (int q = 0; q < 4; ++q) acc[q] = make_float4(0.f, 0.f, 0.f, 0.f);
    float m = -INFINITY, Z = 0.f;

    const int wslot = blk * 4 + wave;          // 0..511
    const float* fc = feats + (size_t)c * NPER * DIM;

    f4 fA[4], fB[4];
    {
        const f4* f4p = (const f4*)(fc + (size_t)wslot * DIM);
        #pragma unroll
        for (int q = 0; q < 4; ++q) fA[q] = __builtin_nontemporal_load(f4p + lane + 64*q);
    }

    #define K1_PROCESS(FREG, ROW)                                              \
    do {                                                                       \
        float p = 0.f;                                                         \
        _Pragma("unroll")                                                      \
        for (int q = 0; q < 4; ++q)                                            \
            p += FREG[q].x*wv[q].x + FREG[q].y*wv[q].y +                       \
                 FREG[q].z*wv[q].z + FREG[q].w*wv[q].w;                        \
        _Pragma("unroll")                                                      \
        for (int off = 32; off > 0; off >>= 1) p += __shfl_xor(p, off, 64);    \
        if (lane == 0) {                                                       \
            unsigned int b = __float_as_uint(p);                               \
            unsigned int u = b ^ ((b & 0x80000000u) ? 0xFFFFFFFFu : 0x80000000u); \
            keys[c * NPER + (ROW)] = ((u64)u << 32) | (unsigned int)(~(ROW));  \
        }                                                                      \
        if (p > m) {   /* wave-uniform; rare after first rows */               \
            const float sOld = __expf(m - p);                                  \
            Z = Z * sOld + 1.f;                                                \
            _Pragma("unroll")                                                  \
            for (int q = 0; q < 4; ++q) {                                      \
                acc[q].x = acc[q].x * sOld + FREG[q].x;                        \
                acc[q].y = acc[q].y * sOld + FREG[q].y;                        \
                acc[q].z = acc[q].z * sOld + FREG[q].z;                        \
                acc[q].w = acc[q].w * sOld + FREG[q].w;                        \
            }                                                                  \
            m = p;                                                             \
        } else {                                                               \
            const float t = __expf(p - m);                                     \
            Z += t;                                                            \
            _Pragma("unroll")                                                  \
            for (int q = 0; q < 4; ++q) {                                      \
                acc[q].x += t * FREG[q].x;                                     \
                acc[q].y += t * FREG[q].y;                                     \
                acc[q].z += t * FREG[q].z;                                     \
                acc[q].w += t * FREG[q].w;                                     \
            }                                                                  \
        }                                                                      \
    } while (0)

    for (int it = 0; it < 8; it += 2) {
        const int r0 = wslot + 512 * it;
        {   // prefetch next row
            const f4* f4p = (const f4*)(fc + (size_t)(r0 + 512) * DIM);
            #pragma unroll
            for (int q = 0; q < 4; ++q) fB[q] = __builtin_nontemporal_load(f4p + lane + 64*q);
        }
        K1_PROCESS(fA, r0);
        if (it + 2 < 8) {
            const f4* f4p = (const f4*)(fc + (size_t)(r0 + 1024) * DIM);
            #pragma unroll
            for (int q = 0; q < 4; ++q) fA[q] = __builtin_nontemporal_load(f4p + lane + 64*q);
        }
        K1_PROCESS(fB, r0 + 512);
    }
    #undef K1_PROCESS

    __shared__ float sm[4], sz[4];
    __shared__ float sacc[4][DIM];
    if (lane == 0) { sm[wave] = m; sz[wave] = Z; }
    #pragma unroll
    for (int q = 0; q < 4; ++q)
        ((float4*)sacc[wave])[lane + 64*q] = acc[q];
    __syncthreads();

    const float mb = fmaxf(fmaxf(sm[0], sm[1]), fmaxf(sm[2], sm[3]));
    const float e0 = __expf(sm[0] - mb), e1 = __expf(sm[1] - mb);
    const float e2 = __expf(sm[2] - mb), e3 = __expf(sm[3] - mb);
    float4 a0 = ((float4*)sacc[0])[tid];
    float4 a1 = ((float4*)sacc[1])[tid];
    float4 a2 = ((float4*)sacc[2])[tid];
    float4 a3 = ((float4*)sacc[3])[tid];
    float4 o;
    o.x = a0.x*e0 + a1.x*e1 + a2.x*e2 + a3.x*e3;
    o.y = a0.y*e0 + a1.y*e1 + a2.y*e2 + a3.y*e3;
    o.z = a0.z*e0 + a1.z*e1 + a2.z*e2 + a3.z*e3;
    o.w = a0.w*e0 + a1.w*e1 + a2.w*e2 + a3.w*e3;
    ((float4*)(pacc + (size_t)(c * K1B + blk) * DIM))[tid] = o;
    if (tid == 0) {
        pm[c * K1B + blk] = mb;
        pz[c * K1B + blk] = sz[0]*e0 + sz[1]*e1 + sz[2]*e2 + sz[3]*e3;
    }
}

// ---------------- FAT A: blocks 0..31 = k2_combine; 32..543 = k3a_rank ----------
__global__ __launch_bounds__(256) void fat_a(
    const float* __restrict__ pacc, const float* __restrict__ pm,
    const float* __restrict__ pz, float* __restrict__ g,
    const u64* __restrict__ keys, int* __restrict__ part) // part (JS,8c,4096)
{
    const int tid = threadIdx.x;
    if (blockIdx.x < 32) {
        // ---- k2: combine block partials -> g_c = A^T feats ----
        const int c = blockIdx.x >> 2, jb = blockIdx.x & 3;
        const int slot = tid & 63;
        const int bg   = tid >> 6;         // 0..3, each handles 32 partials
        __shared__ float spm[K1B], spz[K1B], swe[K1B];
        __shared__ float szc;
        __shared__ float4 sred[3][64];

        if (tid < K1B) spm[tid] = pm[c*K1B + tid];
        else spz[tid - K1B] = pz[c*K1B + tid - K1B];
        __syncthreads();
        float mc = -INFINITY;
        for (int b = 0; b < K1B; ++b) mc = fmaxf(mc, spm[b]);
        if (tid < K1B) swe[tid] = __expf(spm[tid] - mc);
        __syncthreads();
        if (tid == 0) {
            float z = 0.f;
            for (int b = 0; b < K1B; ++b) z += spz[b] * swe[b];
            szc = z;
        }

        const int jbase = jb * 256 + slot * 4;
        float4 a = make_float4(0.f, 0.f, 0.f, 0.f);
        #pragma unroll
        for (int k = 0; k < 32; ++k) {
            const int b = bg * 32 + k;
            const float e = swe[b];
            float4 v = *(const float4*)(pacc + (size_t)(c*K1B + b) * DIM + jbase);
            a.x += e*v.x; a.y += e*v.y; a.z += e*v.z; a.w += e*v.w;
        }
        if (bg) sred[bg-1][slot] = a;
        __syncthreads();
        if (bg == 0) {
            float4 t0 = sred[0][slot], t1 = sred[1][slot], t2 = sred[2][slot];
            const float inv = 1.0f / szc;
            float4 o;
            o.x = (a.x + t0.x + t1.x + t2.x) * inv;
            o.y = (a.y + t0.y + t1.y + t2.y) * inv;
            o.z = (a.z + t0.z + t1.z + t2.z) * inv;
            o.w = (a.w + t0.w + t1.w + t2.w) * inv;
            *(float4*)(g + c * DIM + jbase) = o;
        }
    } else {
        // ---- k3a: partial rank counts; grid 4 iblk x JS x 8 c ----
        const int t = blockIdx.x - 32;
        const int iblk = t & 3, js = (t >> 2) & (JS-1), c = t >> 6;
        __shared__ u64 lk[256];            // 256-key j-slice
        if (tid < 128)
            ((float4*)lk)[tid] = ((const float4*)(keys + c * NPER + js * 256))[tid];

        const int ibase = iblk * 1024;
        u64 ki[4];
        #pragma unroll
        for (int q = 0; q < 4; ++q) ki[q] = keys[c * NPER + ibase + tid + 256*q];
        __syncthreads();

        int cnt0 = 0, cnt1 = 0, cnt2 = 0, cnt3 = 0;
        const ull2* lk2 = (const ull2*)lk;
        #pragma unroll 4
        for (int jt = 0; jt < 128; ++jt) {
            ull2 kj = lk2[jt];             // wave-uniform broadcast, conflict-free
            cnt0 += (kj.x > ki[0]) + (kj.y > ki[0]);
            cnt1 += (kj.x > ki[1]) + (kj.y > ki[1]);
            cnt2 += (kj.x > ki[2]) + (kj.y > ki[2]);
            cnt3 += (kj.x > ki[3]) + (kj.y > ki[3]);
        }
        int* dst = part + ((js * NC + c) << 12) + ibase + tid;
        dst[0]   = cnt0; dst[256] = cnt1; dst[512] = cnt2; dst[768] = cnt3;
    }
}

// ---------------- FAT B: blocks 0..127 = k3b_gather; 128..255 = k5_fusion ------
__global__ __launch_bounds__(256) void fat_b(
    const int* __restrict__ part, const float* __restrict__ feats,
    float* __restrict__ out_sel,
    const float* __restrict__ v_w, const float* __restrict__ v_b,
    const float* __restrict__ g, float* __restrict__ fus)
{
    const int tid = threadIdx.x;
    if (blockIdx.x < 128) {
        // ---- k3b: sum ranks + gather selected rows (software-pipelined) ----
        const int c = blockIdx.x >> 4;
        const int i = (blockIdx.x & 15) * 256 + tid;
        __shared__ int list_i[TOPK], list_r[TOPK];
        __shared__ int cnt;
        if (tid == 0) cnt = 0;
        __syncthreads();

        int r = 0;
        #pragma unroll
        for (int js = 0; js < JS; ++js) r += part[((js * NC + c) << 12) + i];
        if (r < TOPK) {
            const int s = atomicAdd(&cnt, 1);
            list_i[s] = i; list_r[s] = r;
        }
        __syncthreads();

        const int n = cnt;
        if (n > 0) {
            const float* fc = feats + (size_t)c * NPER * DIM;
            float4 cur = ((const float4*)(fc + (size_t)list_i[0] * DIM))[tid];
            for (int s = 0; s < n; ++s) {
                float4 nxt;
                if (s + 1 < n)   // prefetch next row while storing current
                    nxt = ((const float4*)(fc + (size_t)list_i[s+1] * DIM))[tid];
                ((float4*)(out_sel + ((size_t)c * TOPK + list_r[s]) * DIM))[tid] = cur;
                cur = nxt;
            }
        }
    } else {
        // ---- k5: fus = v_w @ g + v_b, one pass over v_w ----
        __shared__ float4 sg[NC][256];     // 32 KB
        const int lane = tid & 63, wave = tid >> 6;
        for (int t = tid; t < NC * 256; t += 256)
            ((float4*)sg)[t] = ((const float4*)g)[t];
        __syncthreads();

        const int row0 = (blockIdx.x - 128) * 8 + wave * 2;
        for (int rr = 0; rr < 2; ++rr) {
            const int o = row0 + rr;
            const float4* vr = (const float4*)(v_w + (size_t)o * DIM);
            float4 v[4];
            #pragma unroll
            for (int u = 0; u < 4; ++u) v[u] = vr[lane + 64*u];
            float p[NC];
            #pragma unroll
            for (int cc = 0; cc < NC; ++cc) {
                float s = 0.f;
                #pragma unroll
                for (int u = 0; u < 4; ++u) {
                    float4 gv = sg[cc][lane + 64*u];
                    s += v[u].x*gv.x + v[u].y*gv.y + v[u].z*gv.z + v[u].w*gv.w;
                }
                p[cc] = s;
            }
            #pragma unroll
            for (int off = 32; off > 0; off >>= 1) {
                #pragma unroll
                for (int cc = 0; cc < NC; ++cc) p[cc] += __shfl_xor(p[cc], off, 64);
            }
            if (lane == 0) {
                const float b = v_b[o];
                #pragma unroll
                for (int cc = 0; cc < NC; ++cc) fus[cc * DIM + o] = p[cc] + b;
            }
        }
    }
}

extern "C" void kernel_launch(void* const* d_in, const int* in_sizes, int n_in,
                              void* d_out, int out_size, void* d_ws, size_t ws_size,
                              hipStream_t stream) {
    const float* feats     = (const float*)d_in[0];
    const float* key_feats = (const float*)d_in[1];
    const float* q_w       = (const float*)d_in[2];
    const float* q_b       = (const float*)d_in[3];
    const float* v_w       = (const float*)d_in[4];
    const float* v_b       = (const float*)d_in[5];
    float* out      = (float*)d_out;
    float* out_sel  = out;
    float* out_fus  = out + (size_t)1024 * 1024;

    // workspace layout (8B-aligned first)
    u64*   keys   = (u64*)d_ws;                          // 256 KB
    float* pacc   = (float*)(keys + NC * NPER);          // 4 MB
    float* pm     = pacc + (size_t)NC * K1B * DIM;       // 1024
    float* pz     = pm + NC * K1B;                       // 1024
    float* g      = pz + NC * K1B;                       // 8*1024
    float* w_all  = g + NC * DIM;                        // 8*1024
    int*   part   = (int*)(w_all + NC * DIM);            // JS*8*4096 ints = 2 MB

    k0_prep <<<dim3(NC * 4),       256, 0, stream>>>(key_feats, q_w, q_b, w_all);
    k1_main <<<dim3(K1B, NC),      256, 0, stream>>>(feats, w_all, keys, pacc, pm, pz);
    fat_a   <<<dim3(32 + 4*JS*NC), 256, 0, stream>>>(pacc, pm, pz, g, keys, part);
    fat_b   <<<dim3(256),          256, 0, stream>>>(part, feats, out_sel, v_w, v_b, g, out_fus);
}